// Round 1
// baseline (869.846 us; speedup 1.0000x reference)
//
#include <hip/hip_runtime.h>

// ============================================================================
// Fused LSTM decoder, MI355X (gfx950).
// One persistent-tile kernel: init GEMMs (h0,c0 from z) + 8 recurrent steps,
// all in bf16 MFMA (v_mfma_f32_32x32x16_bf16) with fp32 cell state in VGPRs.
//
// Per workgroup (512 thr = 8 waves): 64 batch rows.
//   - LDS A-tile [64][360] bf16: cols 0..71 = x (fed-back y), 72..95 = zero pad,
//     96..351 = h. Stride 360 -> uniform bank use for ds_read_b128.
//   - Wave w owns channels [32w,32w+32): computes gate cols {J, J+256, J+512,
//     J+768} so i,f,g,o for one (row,ch) land in the SAME lane -> c update is
//     pure in-lane VALU, c never leaves registers across steps.
//   - Weights repacked once per launch by prep_kernel into d_ws as bf16:
//     Wcat[1024][352] = [W_ih | 0pad | W_hh], Whc[512][256] = [Wh;Wc],
//     Wob[96][256] = Wo zero-padded, bsum = b_ih+b_hh, bop = bo padded.
//     B-fragments load 16B/lane straight from L2 (weights ~1MB, L2-resident).
// Predicted: ~100-160us, L2-read-bound; MfmaUtil ~20-25%.
// ============================================================================

#define HID   256
#define INP   72
#define NSTEP 8
#define MT    64      // batch rows per workgroup
#define KA    352     // padded K for gates GEMM (96 + 256)
#define LDA   360     // LDS A-tile row stride in bf16 (padded)
#define NG    1024    // 4*HID gates

typedef __attribute__((ext_vector_type(8)))  short bf16x8;   // MFMA A/B frag
typedef __attribute__((ext_vector_type(16))) float f32x16;   // MFMA C/D frag

__device__ __forceinline__ short f2bf(float x) {  // fp32 -> bf16 bits, RNE
  unsigned int u = __builtin_bit_cast(unsigned int, x);
  unsigned int r = (u + 0x7fffu + ((u >> 16) & 1u)) >> 16;
  return (short)r;
}
__device__ __forceinline__ float fsig(float x) {
  return __builtin_amdgcn_rcpf(1.0f + __builtin_amdgcn_exp2f(-1.44269504f * x));
}
__device__ __forceinline__ float ftanh(float x) {
  return 1.0f - 2.0f * __builtin_amdgcn_rcpf(1.0f + __builtin_amdgcn_exp2f(2.88539008f * x));
}

// ---------------------------------------------------------------------------
// Weight repack: fp32 -> bf16, fused/padded layouts. Runs every launch (cheap).
// ---------------------------------------------------------------------------
__global__ void prep_kernel(const float* __restrict__ W_ih, const float* __restrict__ W_hh,
                            const float* __restrict__ b_ih, const float* __restrict__ b_hh,
                            const float* __restrict__ Wh,   const float* __restrict__ Wc,
                            const float* __restrict__ Wo,   const float* __restrict__ bo,
                            short* __restrict__ Wcat, short* __restrict__ Whc,
                            short* __restrict__ Wob,  float* __restrict__ bsum,
                            float* __restrict__ bop) {
  int i = blockIdx.x * 256 + threadIdx.x;
  if (i < NG * KA) {                       // Wcat[1024][352]
    int n = i / KA, k = i - n * KA;
    float v = (k < INP) ? W_ih[n * INP + k]
                        : (k < 96 ? 0.0f : W_hh[n * HID + (k - 96)]);
    Wcat[i] = f2bf(v);
  }
  if (i < 512 * HID) {                     // Whc[512][256] = [Wh ; Wc]
    int n = i >> 8, k = i & 255;
    float v = (n < 256) ? Wh[n * HID + k] : Wc[(n - 256) * HID + k];
    Whc[i] = f2bf(v);
  }
  if (i < 96 * HID) {                      // Wob[96][256], rows 72..95 zero
    int n = i >> 8, k = i & 255;
    Wob[i] = f2bf(n < INP ? Wo[n * HID + k] : 0.0f);
  }
  if (i < NG) bsum[i] = b_ih[i] + b_hh[i];
  if (i < 96) bop[i] = (i < INP) ? bo[i] : 0.0f;
}

// ---------------------------------------------------------------------------
// Main fused kernel.
// ---------------------------------------------------------------------------
__global__ __launch_bounds__(512, 2) void lstm_kernel(
    const float* __restrict__ z,    const short* __restrict__ Wcat,
    const short* __restrict__ Whc,  const short* __restrict__ Wob,
    const float* __restrict__ bsum, const float* __restrict__ bh,
    const float* __restrict__ bc,   const float* __restrict__ bop,
    float* __restrict__ out) {
  __shared__ short Alds[MT * LDA];          // 46080 B

  const int tid  = threadIdx.x;
  const int w    = tid >> 6;                // wave 0..7
  const int lane = tid & 63;
  const int l31  = lane & 31;
  const int lh   = lane >> 5;               // lane half (k-offset selector)
  const int wg   = blockIdx.x;

  // ---- stage z tile into h-region (bf16) + zero x-region -------------------
  const float4* z4 = reinterpret_cast<const float4*>(z + (size_t)wg * MT * HID);
#pragma unroll
  for (int it = 0; it < 8; ++it) {          // 4096 float4 = 64 rows x 256 cols
    int i = tid + it * 512;
    float4 v = z4[i];
    int row = i >> 6;
    int c0  = (i & 63) << 2;
    ushort4 p;
    p.x = (unsigned short)f2bf(v.x); p.y = (unsigned short)f2bf(v.y);
    p.z = (unsigned short)f2bf(v.z); p.w = (unsigned short)f2bf(v.w);
    *reinterpret_cast<ushort4*>(&Alds[row * LDA + 96 + c0]) = p;
  }
#pragma unroll
  for (int it = 0; it < 6; ++it) {          // zero x-region cols [0,96)
    int i = tid + it * 512;                 // 3072 dword writes
    int row = i / 48;
    int c2  = (i - row * 48) << 1;
    *reinterpret_cast<unsigned int*>(&Alds[row * LDA + c2]) = 0u;
  }
  __syncthreads();

  const int   ch    = w * 32 + l31;         // this lane's channel
  const short* Arow0 = &Alds[l31 * LDA];
  const short* Arow1 = &Alds[(32 + l31) * LDA];

  // ---- init GEMM: h0 = z@Wh^T + bh ; c0 = z@Wc^T + bc ----------------------
  const short* Bh = Whc + (size_t)ch * HID + lh * 8;
  const short* Bc = Whc + (size_t)(256 + ch) * HID + lh * 8;
  f32x16 ah0 = f32x16{}, ah1 = f32x16{}, ac0 = f32x16{}, ac1 = f32x16{};
#pragma unroll
  for (int kc = 0; kc < 16; ++kc) {
    int k = kc * 16 + lh * 8;
    bf16x8 a0 = *reinterpret_cast<const bf16x8*>(Arow0 + 96 + k);
    bf16x8 a1 = *reinterpret_cast<const bf16x8*>(Arow1 + 96 + k);
    bf16x8 b0 = *reinterpret_cast<const bf16x8*>(Bh + kc * 16);
    bf16x8 b1 = *reinterpret_cast<const bf16x8*>(Bc + kc * 16);
    ah0 = __builtin_amdgcn_mfma_f32_32x32x16_bf16(a0, b0, ah0, 0, 0, 0);
    ah1 = __builtin_amdgcn_mfma_f32_32x32x16_bf16(a1, b0, ah1, 0, 0, 0);
    ac0 = __builtin_amdgcn_mfma_f32_32x32x16_bf16(a0, b1, ac0, 0, 0, 0);
    ac1 = __builtin_amdgcn_mfma_f32_32x32x16_bf16(a1, b1, ac1, 0, 0, 0);
  }
  const float bhv = bh[ch];
  const float bcv = bc[ch];
  float cst[2][16];                          // fp32 cell state, in-lane forever
#pragma unroll
  for (int r = 0; r < 16; ++r) { cst[0][r] = ac0[r] + bcv; cst[1][r] = ac1[r] + bcv; }
  __syncthreads();                           // all init-GEMM LDS reads done
#pragma unroll
  for (int m = 0; m < 2; ++m)
#pragma unroll
    for (int r = 0; r < 16; ++r) {
      int row = m * 32 + (r & 3) + ((r >> 2) << 3) + lh * 4;  // C/D row map
      float h0 = (m == 0 ? ah0[r] : ah1[r]) + bhv;
      Alds[row * LDA + 96 + ch] = f2bf(h0);
    }
  __syncthreads();

  // ---- per-step constants --------------------------------------------------
  const short* Bg0 = Wcat + (size_t)(0 * 256 + ch) * KA + lh * 8;
  const short* Bg1 = Wcat + (size_t)(1 * 256 + ch) * KA + lh * 8;
  const short* Bg2 = Wcat + (size_t)(2 * 256 + ch) * KA + lh * 8;
  const short* Bg3 = Wcat + (size_t)(3 * 256 + ch) * KA + lh * 8;
  const float bi_ = bsum[0 * 256 + ch];
  const float bf_ = bsum[1 * 256 + ch];
  const float bg_ = bsum[2 * 256 + ch];
  const float bo_ = bsum[3 * 256 + ch];

  const int   m2  = w / 3;                   // GEMM2 tile (valid for w<6)
  const int   n2  = w - m2 * 3;
  const float bov = (w < 6) ? bop[n2 * 32 + l31] : 0.0f;
  const short* BoP = Wob + (size_t)((w < 6 ? n2 * 32 + l31 : 0)) * HID + lh * 8;
  float* outp = out + (size_t)wg * MT * (NSTEP * INP);

  // ---- 8 recurrent steps ---------------------------------------------------
  for (int t = 0; t < NSTEP; ++t) {
    // GEMM1: gates[64 x 128cols] = A[64 x 352] @ Wcat^T slice, K-chunks of 16
    f32x16 acc[2][4];
#pragma unroll
    for (int m = 0; m < 2; ++m)
#pragma unroll
      for (int q = 0; q < 4; ++q) acc[m][q] = f32x16{};
#pragma unroll
    for (int kc = 0; kc < 22; ++kc) {
      int k = kc * 16 + lh * 8;
      bf16x8 a0 = *reinterpret_cast<const bf16x8*>(Arow0 + k);
      bf16x8 a1 = *reinterpret_cast<const bf16x8*>(Arow1 + k);
      bf16x8 b0 = *reinterpret_cast<const bf16x8*>(Bg0 + kc * 16);
      bf16x8 b1 = *reinterpret_cast<const bf16x8*>(Bg1 + kc * 16);
      bf16x8 b2 = *reinterpret_cast<const bf16x8*>(Bg2 + kc * 16);
      bf16x8 b3 = *reinterpret_cast<const bf16x8*>(Bg3 + kc * 16);
      acc[0][0] = __builtin_amdgcn_mfma_f32_32x32x16_bf16(a0, b0, acc[0][0], 0, 0, 0);
      acc[1][0] = __builtin_amdgcn_mfma_f32_32x32x16_bf16(a1, b0, acc[1][0], 0, 0, 0);
      acc[0][1] = __builtin_amdgcn_mfma_f32_32x32x16_bf16(a0, b1, acc[0][1], 0, 0, 0);
      acc[1][1] = __builtin_amdgcn_mfma_f32_32x32x16_bf16(a1, b1, acc[1][1], 0, 0, 0);
      acc[0][2] = __builtin_amdgcn_mfma_f32_32x32x16_bf16(a0, b2, acc[0][2], 0, 0, 0);
      acc[1][2] = __builtin_amdgcn_mfma_f32_32x32x16_bf16(a1, b2, acc[1][2], 0, 0, 0);
      acc[0][3] = __builtin_amdgcn_mfma_f32_32x32x16_bf16(a0, b3, acc[0][3], 0, 0, 0);
      acc[1][3] = __builtin_amdgcn_mfma_f32_32x32x16_bf16(a1, b3, acc[1][3], 0, 0, 0);
    }
    __syncthreads();   // every wave done reading x/h for this step

    // elementwise: i,f,g,o for (row,ch) are all in-lane; c stays in registers
#pragma unroll
    for (int m = 0; m < 2; ++m)
#pragma unroll
      for (int r = 0; r < 16; ++r) {
        float iv = fsig (acc[m][0][r] + bi_);
        float fv = fsig (acc[m][1][r] + bf_);
        float gv = ftanh(acc[m][2][r] + bg_);
        float ov = fsig (acc[m][3][r] + bo_);
        float cc = fv * cst[m][r] + iv * gv;
        cst[m][r] = cc;
        float hv = ov * ftanh(cc);
        int row = m * 32 + (r & 3) + ((r >> 2) << 3) + lh * 4;
        Alds[row * LDA + 96 + ch] = f2bf(hv);
      }
    __syncthreads();   // h fully updated

    // GEMM2: y = sigmoid(h @ Wo^T + bo); feed back as x, store to out
    if (w < 6) {
      f32x16 y = f32x16{};
      const short* Arow2 = &Alds[(m2 * 32 + l31) * LDA + 96];
#pragma unroll
      for (int kc = 0; kc < 16; ++kc) {
        int k = kc * 16 + lh * 8;
        bf16x8 a = *reinterpret_cast<const bf16x8*>(Arow2 + k);
        bf16x8 b = *reinterpret_cast<const bf16x8*>(BoP + kc * 16);
        y = __builtin_amdgcn_mfma_f32_32x32x16_bf16(a, b, y, 0, 0, 0);
      }
      int col = n2 * 32 + l31;
#pragma unroll
      for (int r = 0; r < 16; ++r) {
        float yv = fsig(y[r] + bov);
        int row = m2 * 32 + (r & 3) + ((r >> 2) << 3) + lh * 4;
        if (col < INP) {
          outp[(size_t)row * (NSTEP * INP) + t * INP + col] = yv;
          Alds[row * LDA + col] = f2bf(yv);   // next step's x
        }
      }
    }
    __syncthreads();   // x ready for next step
  }
}

// ---------------------------------------------------------------------------
extern "C" void kernel_launch(void* const* d_in, const int* in_sizes, int n_in,
                              void* d_out, int out_size, void* d_ws, size_t ws_size,
                              hipStream_t stream) {
  const float* z    = (const float*)d_in[0];
  const float* W_ih = (const float*)d_in[1];
  const float* W_hh = (const float*)d_in[2];
  const float* b_ih = (const float*)d_in[3];
  const float* b_hh = (const float*)d_in[4];
  const float* Wh   = (const float*)d_in[5];
  const float* bh   = (const float*)d_in[6];
  const float* Wc   = (const float*)d_in[7];
  const float* bc   = (const float*)d_in[8];
  const float* Wo   = (const float*)d_in[9];
  const float* bo   = (const float*)d_in[10];

  const int B = in_sizes[0] / HID;

  // d_ws layout (bytes): needs ~1.04 MB total
  char*  ws   = (char*)d_ws;
  short* Wcat = (short*)(ws);                 // 1024*352*2 = 720896
  short* Whc  = (short*)(ws + 720896);        // 512*256*2  = 262144
  short* Wob  = (short*)(ws + 983040);        // 96*256*2   = 49152
  float* bsum = (float*)(ws + 1032192);       // 1024*4     = 4096
  float* bop  = (float*)(ws + 1036288);       // 96*4       = 384

  prep_kernel<<<1408, 256, 0, stream>>>(W_ih, W_hh, b_ih, b_hh, Wh, Wc, Wo, bo,
                                        Wcat, Whc, Wob, bsum, bop);
  lstm_kernel<<<B / MT, 512, 0, stream>>>(z, Wcat, Whc, Wob, bsum, bh, bc, bop,
                                          (float*)d_out);
}

// Round 3
// 698.934 us; speedup vs baseline: 1.2445x; 1.2445x over previous
//
#include <hip/hip_runtime.h>

// ============================================================================
// Fused LSTM decoder, MI355X (gfx950). R3 (= R2 with NT-builtin type fix).
// R1 post-mortem: 782us, FETCH 1.19GB (weights evicted from L2 by the 365MB
// scattered output-write stream), MfmaUtil 11%, latency-bound at 2 waves/SIMD.
// Changes vs R1:
//   - y staged per-step in LDS (f32), written out with nontemporal float4
//     stores (no L2 allocation -> weights stay L2-resident).
//   - z staged with nontemporal loads (read-once, don't pollute L2).
//   - skip all-zero K-slice kc==5 in GEMM1.
//   - NT builtins use ext_vector_type(4) float (HIP float4 class rejected).
// Predicted: FETCH -> ~60MB, WRITE -> ~100MB, MfmaUtil 30-45%, dur ~200us.
// ============================================================================

#define HID   256
#define INP   72
#define NSTEP 8
#define MT    64      // batch rows per workgroup
#define KA    352     // padded K for gates GEMM (96 + 256)
#define LDA   360     // LDS A-tile row stride in bf16 (padded)
#define NG    1024    // 4*HID gates

typedef __attribute__((ext_vector_type(8)))  short bf16x8;   // MFMA A/B frag
typedef __attribute__((ext_vector_type(16))) float f32x16;   // MFMA C/D frag
typedef __attribute__((ext_vector_type(4)))  float f32x4;    // NT load/store

__device__ __forceinline__ short f2bf(float x) {  // fp32 -> bf16 bits, RNE
  unsigned int u = __builtin_bit_cast(unsigned int, x);
  unsigned int r = (u + 0x7fffu + ((u >> 16) & 1u)) >> 16;
  return (short)r;
}
__device__ __forceinline__ float fsig(float x) {
  return __builtin_amdgcn_rcpf(1.0f + __builtin_amdgcn_exp2f(-1.44269504f * x));
}
__device__ __forceinline__ float ftanh(float x) {
  return 1.0f - 2.0f * __builtin_amdgcn_rcpf(1.0f + __builtin_amdgcn_exp2f(2.88539008f * x));
}

// ---------------------------------------------------------------------------
// Weight repack: fp32 -> bf16, fused/padded layouts. Runs every launch (cheap).
// ---------------------------------------------------------------------------
__global__ void prep_kernel(const float* __restrict__ W_ih, const float* __restrict__ W_hh,
                            const float* __restrict__ b_ih, const float* __restrict__ b_hh,
                            const float* __restrict__ Wh,   const float* __restrict__ Wc,
                            const float* __restrict__ Wo,   const float* __restrict__ bo,
                            short* __restrict__ Wcat, short* __restrict__ Whc,
                            short* __restrict__ Wob,  float* __restrict__ bsum,
                            float* __restrict__ bop) {
  int i = blockIdx.x * 256 + threadIdx.x;
  if (i < NG * KA) {                       // Wcat[1024][352]
    int n = i / KA, k = i - n * KA;
    float v = (k < INP) ? W_ih[n * INP + k]
                        : (k < 96 ? 0.0f : W_hh[n * HID + (k - 96)]);
    Wcat[i] = f2bf(v);
  }
  if (i < 512 * HID) {                     // Whc[512][256] = [Wh ; Wc]
    int n = i >> 8, k = i & 255;
    float v = (n < 256) ? Wh[n * HID + k] : Wc[(n - 256) * HID + k];
    Whc[i] = f2bf(v);
  }
  if (i < 96 * HID) {                      // Wob[96][256], rows 72..95 zero
    int n = i >> 8, k = i & 255;
    Wob[i] = f2bf(n < INP ? Wo[n * HID + k] : 0.0f);
  }
  if (i < NG) bsum[i] = b_ih[i] + b_hh[i];
  if (i < 96) bop[i] = (i < INP) ? bo[i] : 0.0f;
}

// ---------------------------------------------------------------------------
// Main fused kernel.
// ---------------------------------------------------------------------------
__global__ __launch_bounds__(512, 2) void lstm_kernel(
    const float* __restrict__ z,    const short* __restrict__ Wcat,
    const short* __restrict__ Whc,  const short* __restrict__ Wob,
    const float* __restrict__ bsum, const float* __restrict__ bh,
    const float* __restrict__ bc,   const float* __restrict__ bop,
    float* __restrict__ out) {
  __shared__ short Alds[MT * LDA];          // 46080 B
  __shared__ float ybuf[MT][INP];           // 18432 B (total 64512 <= 64KB)

  const int tid  = threadIdx.x;
  const int w    = tid >> 6;                // wave 0..7
  const int lane = tid & 63;
  const int l31  = lane & 31;
  const int lh   = lane >> 5;               // lane half (k-offset selector)
  const int wg   = blockIdx.x;

  // ---- stage z tile into h-region (bf16, NT loads) + zero x-region ---------
  const f32x4* z4 = reinterpret_cast<const f32x4*>(z + (size_t)wg * MT * HID);
#pragma unroll
  for (int it = 0; it < 8; ++it) {          // 4096 float4 = 64 rows x 256 cols
    int i = tid + it * 512;
    f32x4 v = __builtin_nontemporal_load(&z4[i]);
    int row = i >> 6;
    int c0  = (i & 63) << 2;
    ushort4 p;
    p.x = (unsigned short)f2bf(v.x); p.y = (unsigned short)f2bf(v.y);
    p.z = (unsigned short)f2bf(v.z); p.w = (unsigned short)f2bf(v.w);
    *reinterpret_cast<ushort4*>(&Alds[row * LDA + 96 + c0]) = p;
  }
#pragma unroll
  for (int it = 0; it < 6; ++it) {          // zero x-region cols [0,96)
    int i = tid + it * 512;                 // 3072 dword writes
    int row = i / 48;
    int c2  = (i - row * 48) << 1;
    *reinterpret_cast<unsigned int*>(&Alds[row * LDA + c2]) = 0u;
  }
  __syncthreads();

  const int   ch    = w * 32 + l31;         // this lane's channel
  const short* Arow0 = &Alds[l31 * LDA];
  const short* Arow1 = &Alds[(32 + l31) * LDA];

  // ---- init GEMM: h0 = z@Wh^T + bh ; c0 = z@Wc^T + bc ----------------------
  const short* Bh = Whc + (size_t)ch * HID + lh * 8;
  const short* Bc = Whc + (size_t)(256 + ch) * HID + lh * 8;
  f32x16 ah0 = f32x16{}, ah1 = f32x16{}, ac0 = f32x16{}, ac1 = f32x16{};
#pragma unroll
  for (int kc = 0; kc < 16; ++kc) {
    int k = kc * 16 + lh * 8;
    bf16x8 a0 = *reinterpret_cast<const bf16x8*>(Arow0 + 96 + k);
    bf16x8 a1 = *reinterpret_cast<const bf16x8*>(Arow1 + 96 + k);
    bf16x8 b0 = *reinterpret_cast<const bf16x8*>(Bh + kc * 16);
    bf16x8 b1 = *reinterpret_cast<const bf16x8*>(Bc + kc * 16);
    ah0 = __builtin_amdgcn_mfma_f32_32x32x16_bf16(a0, b0, ah0, 0, 0, 0);
    ah1 = __builtin_amdgcn_mfma_f32_32x32x16_bf16(a1, b0, ah1, 0, 0, 0);
    ac0 = __builtin_amdgcn_mfma_f32_32x32x16_bf16(a0, b1, ac0, 0, 0, 0);
    ac1 = __builtin_amdgcn_mfma_f32_32x32x16_bf16(a1, b1, ac1, 0, 0, 0);
  }
  const float bhv = bh[ch];
  const float bcv = bc[ch];
  float cst[2][16];                          // fp32 cell state, in-lane forever
#pragma unroll
  for (int r = 0; r < 16; ++r) { cst[0][r] = ac0[r] + bcv; cst[1][r] = ac1[r] + bcv; }
  __syncthreads();                           // all init-GEMM LDS reads done
#pragma unroll
  for (int m = 0; m < 2; ++m)
#pragma unroll
    for (int r = 0; r < 16; ++r) {
      int row = m * 32 + (r & 3) + ((r >> 2) << 3) + lh * 4;  // C/D row map
      float h0 = (m == 0 ? ah0[r] : ah1[r]) + bhv;
      Alds[row * LDA + 96 + ch] = f2bf(h0);
    }
  __syncthreads();

  // ---- per-step constants --------------------------------------------------
  const short* Bg0 = Wcat + (size_t)(0 * 256 + ch) * KA + lh * 8;
  const short* Bg1 = Wcat + (size_t)(1 * 256 + ch) * KA + lh * 8;
  const short* Bg2 = Wcat + (size_t)(2 * 256 + ch) * KA + lh * 8;
  const short* Bg3 = Wcat + (size_t)(3 * 256 + ch) * KA + lh * 8;
  const float bi_ = bsum[0 * 256 + ch];
  const float bf_ = bsum[1 * 256 + ch];
  const float bg_ = bsum[2 * 256 + ch];
  const float bo_ = bsum[3 * 256 + ch];

  const int   m2  = w / 3;                   // GEMM2 tile (valid for w<6)
  const int   n2  = w - m2 * 3;
  const float bov = (w < 6) ? bop[n2 * 32 + l31] : 0.0f;
  const short* BoP = Wob + (size_t)((w < 6 ? n2 * 32 + l31 : 0)) * HID + lh * 8;
  float* outp = out + (size_t)wg * MT * (NSTEP * INP);

  // ---- 8 recurrent steps ---------------------------------------------------
  for (int t = 0; t < NSTEP; ++t) {
    // GEMM1: gates[64 x 128cols] = A[64 x 352] @ Wcat^T slice, K-chunks of 16.
    // kc==5 (cols 80..95) is all zero-pad -> skipped.
    f32x16 acc[2][4];
#pragma unroll
    for (int m = 0; m < 2; ++m)
#pragma unroll
      for (int q = 0; q < 4; ++q) acc[m][q] = f32x16{};
#pragma unroll
    for (int kk = 0; kk < 21; ++kk) {
      int kc = kk + (kk >= 5);
      int k = kc * 16 + lh * 8;
      bf16x8 a0 = *reinterpret_cast<const bf16x8*>(Arow0 + k);
      bf16x8 a1 = *reinterpret_cast<const bf16x8*>(Arow1 + k);
      bf16x8 b0 = *reinterpret_cast<const bf16x8*>(Bg0 + kc * 16);
      bf16x8 b1 = *reinterpret_cast<const bf16x8*>(Bg1 + kc * 16);
      bf16x8 b2 = *reinterpret_cast<const bf16x8*>(Bg2 + kc * 16);
      bf16x8 b3 = *reinterpret_cast<const bf16x8*>(Bg3 + kc * 16);
      acc[0][0] = __builtin_amdgcn_mfma_f32_32x32x16_bf16(a0, b0, acc[0][0], 0, 0, 0);
      acc[1][0] = __builtin_amdgcn_mfma_f32_32x32x16_bf16(a1, b0, acc[1][0], 0, 0, 0);
      acc[0][1] = __builtin_amdgcn_mfma_f32_32x32x16_bf16(a0, b1, acc[0][1], 0, 0, 0);
      acc[1][1] = __builtin_amdgcn_mfma_f32_32x32x16_bf16(a1, b1, acc[1][1], 0, 0, 0);
      acc[0][2] = __builtin_amdgcn_mfma_f32_32x32x16_bf16(a0, b2, acc[0][2], 0, 0, 0);
      acc[1][2] = __builtin_amdgcn_mfma_f32_32x32x16_bf16(a1, b2, acc[1][2], 0, 0, 0);
      acc[0][3] = __builtin_amdgcn_mfma_f32_32x32x16_bf16(a0, b3, acc[0][3], 0, 0, 0);
      acc[1][3] = __builtin_amdgcn_mfma_f32_32x32x16_bf16(a1, b3, acc[1][3], 0, 0, 0);
    }
    __syncthreads();   // every wave done reading x/h for this step

    // elementwise: i,f,g,o for (row,ch) are all in-lane; c stays in registers
#pragma unroll
    for (int m = 0; m < 2; ++m)
#pragma unroll
      for (int r = 0; r < 16; ++r) {
        float iv = fsig (acc[m][0][r] + bi_);
        float fv = fsig (acc[m][1][r] + bf_);
        float gv = ftanh(acc[m][2][r] + bg_);
        float ov = fsig (acc[m][3][r] + bo_);
        float cc = fv * cst[m][r] + iv * gv;
        cst[m][r] = cc;
        float hv = ov * ftanh(cc);
        int row = m * 32 + (r & 3) + ((r >> 2) << 3) + lh * 4;
        Alds[row * LDA + 96 + ch] = f2bf(hv);
      }
    __syncthreads();   // h fully updated

    // GEMM2: y = sigmoid(h @ Wo^T + bo); feed back as x, stage f32 in ybuf
    if (w < 6) {
      f32x16 y = f32x16{};
      const short* Arow2 = &Alds[(m2 * 32 + l31) * LDA + 96];
#pragma unroll
      for (int kc = 0; kc < 16; ++kc) {
        int k = kc * 16 + lh * 8;
        bf16x8 a = *reinterpret_cast<const bf16x8*>(Arow2 + k);
        bf16x8 b = *reinterpret_cast<const bf16x8*>(BoP + kc * 16);
        y = __builtin_amdgcn_mfma_f32_32x32x16_bf16(a, b, y, 0, 0, 0);
      }
      int col = n2 * 32 + l31;
#pragma unroll
      for (int r = 0; r < 16; ++r) {
        float yv = fsig(y[r] + bov);
        int row = m2 * 32 + (r & 3) + ((r >> 2) << 3) + lh * 4;
        if (col < INP) {
          ybuf[row][col] = yv;                // staged for coalesced NT write
          Alds[row * LDA + col] = f2bf(yv);   // next step's x
        }
      }
    }
    __syncthreads();   // x + ybuf ready

    // cooperative NT write of this step's y tile: 1152 float4s, coalesced.
    // out row stride 2304B, step offset t*288B, 16B-aligned chunks.
#pragma unroll
    for (int it = 0; it < 3; ++it) {
      int i = tid + it * 512;
      if (i < MT * (INP / 4)) {               // 64 rows x 18 float4
        int row = i / (INP / 4);
        int c4  = i - row * (INP / 4);
        f32x4 v = *reinterpret_cast<const f32x4*>(&ybuf[row][c4 * 4]);
        __builtin_nontemporal_store(
            v, reinterpret_cast<f32x4*>(outp + (size_t)row * (NSTEP * INP)
                                        + t * INP + c4 * 4));
      }
    }
    // no barrier needed here: next phase that writes ybuf (GEMM2) is two
    // __syncthreads away; next K-loop only touches Alds.
  }
}

// ---------------------------------------------------------------------------
extern "C" void kernel_launch(void* const* d_in, const int* in_sizes, int n_in,
                              void* d_out, int out_size, void* d_ws, size_t ws_size,
                              hipStream_t stream) {
  const float* z    = (const float*)d_in[0];
  const float* W_ih = (const float*)d_in[1];
  const float* W_hh = (const float*)d_in[2];
  const float* b_ih = (const float*)d_in[3];
  const float* b_hh = (const float*)d_in[4];
  const float* Wh   = (const float*)d_in[5];
  const float* bh   = (const float*)d_in[6];
  const float* Wc   = (const float*)d_in[7];
  const float* bc   = (const float*)d_in[8];
  const float* Wo   = (const float*)d_in[9];
  const float* bo   = (const float*)d_in[10];

  const int B = in_sizes[0] / HID;

  // d_ws layout (bytes): ~1.04 MB total
  char*  ws   = (char*)d_ws;
  short* Wcat = (short*)(ws);                 // 1024*352*2 = 720896
  short* Whc  = (short*)(ws + 720896);        // 512*256*2  = 262144
  short* Wob  = (short*)(ws + 983040);        // 96*256*2   = 49152
  float* bsum = (float*)(ws + 1032192);       // 1024*4     = 4096
  float* bop  = (float*)(ws + 1036288);       // 96*4       = 384

  prep_kernel<<<1408, 256, 0, stream>>>(W_ih, W_hh, b_ih, b_hh, Wh, Wc, Wo, bo,
                                        Wcat, Whc, Wob, bsum, bop);
  lstm_kernel<<<B / MT, 512, 0, stream>>>(z, Wcat, Whc, Wob, bsum, bh, bc, bop,
                                          (float*)d_out);
}